// Round 7
// baseline (176.569 us; speedup 1.0000x reference)
//
#include <hip/hip_runtime.h>
#include <hip/hip_bf16.h>

#define BATCH 32
#define LSEQ  512
#define NDIM  1024
#define NSPLIT 16
#define LOG2E 1.4426950408889634f

typedef __attribute__((ext_vector_type(8))) short bf16x8;
typedef __attribute__((ext_vector_type(4))) float f32x4;

__device__ __forceinline__ unsigned short f2bf(float x) {
    __hip_bfloat16 h = __float2bfloat16(x);
    return __builtin_bit_cast(unsigned short, h);
}

__device__ __forceinline__ float exp2_fast(float x) {
    float r;
    asm("v_exp_f32 %0, %1" : "=v"(r) : "v"(x));
    return r;
}

// ---------------------------------------------------------------------------
// Kernel 1: fused X fp32 -> bf16 conversion + s1/s2 partial sums (R6 form)
// ---------------------------------------------------------------------------
__global__ __launch_bounds__(256) void prep_kernel(
    const float* __restrict__ X, const float* __restrict__ W,
    unsigned short* __restrict__ Xb, float* __restrict__ P1, float* __restrict__ P2)
{
    __shared__ float sw[2 * LSEQ];
    int tid = threadIdx.x;
    for (int i = tid; i < 2 * LSEQ; i += 256) sw[i] = W[i];
    __syncthreads();

    int b  = blockIdx.y;
    int sp = blockIdx.x;
    int l0 = sp * (LSEQ / NSPLIT);
    size_t base = ((size_t)b * LSEQ + l0) * NDIM + tid * 4;
    const float* xp = X + base;
    unsigned short* xbp = Xb + base;

    float a0=0,a1=0,a2=0,a3=0, c0=0,c1=0,c2=0,c3=0;
    for (int l = 0; l < LSEQ / NSPLIT; ++l) {
        float4 x = *(const float4*)(xp + (size_t)l * NDIM);
        float w1 = sw[l0 + l], w2 = sw[LSEQ + l0 + l];
        a0 = fmaf(x.x, w1, a0); a1 = fmaf(x.y, w1, a1);
        a2 = fmaf(x.z, w1, a2); a3 = fmaf(x.w, w1, a3);
        c0 = fmaf(x.x, w2, c0); c1 = fmaf(x.y, w2, c1);
        c2 = fmaf(x.z, w2, c2); c3 = fmaf(x.w, w2, c3);
        ushort4 u; u.x = f2bf(x.x); u.y = f2bf(x.y); u.z = f2bf(x.z); u.w = f2bf(x.w);
        *(ushort4*)(xbp + (size_t)l * NDIM) = u;
    }
    size_t po = ((size_t)sp * BATCH + b) * NDIM + tid * 4;
    *(float4*)(P1 + po) = make_float4(a0, a1, a2, a3);
    *(float4*)(P2 + po) = make_float4(c0, c1, c2, c3);
}

// ---------------------------------------------------------------------------
// Kernel 2: fused reduce + softmax stats.
// R7: outputs are LOG2-SCALED for gemm's native v_exp_f32 (2^x):
//   s1' = s1*log2e, s2' = s2*log2e, lrd' = -log2(sum).
//   (lrelu is positive-scale-invariant, so exp2(lrelu(s1'+s2')+lrd')
//    == exp(lrelu(s1+s2))/sum exactly as before, modulo fp rounding.)
// Internal sum math unchanged (unscaled).
// ---------------------------------------------------------------------------
__global__ __launch_bounds__(256) void stats_kernel(
    const float* __restrict__ P1, const float* __restrict__ P2,
    float* __restrict__ s1, float* __restrict__ s2, float* __restrict__ lrd)
{
    __shared__ float s1s[NDIM];
    __shared__ float s2s[128];
    int t = threadIdx.x;
    int b = blockIdx.x >> 3, sl = blockIdx.x & 7;
    int j0 = sl * 128;

    #pragma unroll
    for (int q = 0; q < 4; ++q) {
        int n = q * 256 + t;
        float a = 0.f;
        #pragma unroll
        for (int sp = 0; sp < NSPLIT; ++sp)
            a += P1[((size_t)sp * BATCH + b) * NDIM + n];
        s1s[n] = a;
        if (sl == 0) s1[b * NDIM + n] = a * LOG2E;
    }
    if (t < 128) {
        int j = j0 + t;
        float c = 0.f;
        #pragma unroll
        for (int sp = 0; sp < NSPLIT; ++sp)
            c += P2[((size_t)sp * BATCH + b) * NDIM + j];
        s2s[t] = c;
        s2[b * NDIM + j] = c * LOG2E;
    }
    __syncthreads();

    int jl = t >> 1, half = t & 1;
    int jg = j0 + jl;
    float s2j = s2s[jl];
    float sum = 0.f;
    int i0 = half * 512;
    for (int i = i0; i < i0 + 512; ++i) {
        float v = s1s[i] + s2j;
        v = fmaxf(v, 0.01f * v);          // leaky relu
        if (i == jg) v = 0.f;             // diag of e zeroed before softmax
        sum += __expf(v);
    }
    sum += __shfl_xor(sum, 1);
    if (half == 0) lrd[b * NDIM + jg] = -__log2f(sum);
}

// ---------------------------------------------------------------------------
// Kernel 3 (FUSED GEMM): out[b] = sigmoid( Xb[b] (512x1024) @ B^T ),
//   B[i][j] = exp2( lrelu(s1'_i + s2'_j)[diag->0] + lrd'_j ) generated in-LDS.
//
// ROUND 7 = recombination of proven pieces:
//   * R1's counted-vmcnt discipline (prefetch depth 2, NEVER vmcnt(0) in
//     the loop) — R6's lead-1/vmcnt(0) was the 96us latency exposure.
//   * R5/R6 fusion kept (no Bt array, FETCH ~17MB).
//   * M-tile = 512 (full M): B panel generated ONCE (R5/R6 computed it
//     twice across mt) -> BGEN ~150cyc/wave/tile ~= MFMA 155, overlappable.
//   Tile 512x128, 8 waves (4Mx2N), per-wave 128x64 (acc[8][4], R1-proven),
//   BK=32, grid 256 = 1 block/CU.
//   LDS 120KB: A ring-3 x 32KB @0 | B dbuf-2 x 8KB @98304 | s2s @114688 |
//   lrds @118784.  All addressing = R6's superrow XOR involution
//   (measured SQ_LDS_BANK_CONFLICT = 0).
//   Iter t: STAGE A(t+2)->ring | BGEN B(t+1)->dbuf | COMPUTE(t) |
//           WAITVM(4) (drains A(t+1), leaves A(t+2) in flight) | BARF.
// ---------------------------------------------------------------------------
#define WAITVM(n) asm volatile("s_waitcnt vmcnt(" #n ")" ::: "memory")
#define LGKM0()   asm volatile("s_waitcnt lgkmcnt(0)" ::: "memory")
#define BARF()    do { asm volatile("" ::: "memory");                          \
                       __builtin_amdgcn_s_barrier();                           \
                       asm volatile("" ::: "memory"); } while (0)

#define STAGE(AB) {                                                            \
    _Pragma("unroll")                                                          \
    for (int j = 0; j < 4; ++j) {                                              \
        __builtin_amdgcn_global_load_lds(                                      \
            (const __attribute__((address_space(1))) void*)srcp[j],            \
            (__attribute__((address_space(3))) void*)(LdsC + (AB) * 32768 +    \
                tid * 16 + j * 8192), 16, 0, 0);                               \
        srcp[j] += 64;  /* advance k by 32 bf16 */                             \
    } }

#define BGEN(TT, DN) {                                                         \
    int k0f = (TT) * 32;                                                       \
    const float* s2p = s2s + k0f + kc8;                                        \
    const float* ldp = lrds + k0f + kc8;                                       \
    float4 sa = *(const float4*)(s2p);                                         \
    float4 sb = *(const float4*)(s2p + 4);                                     \
    float4 la = *(const float4*)(ldp);                                         \
    float4 lb = *(const float4*)(ldp + 4);                                     \
    float sv[8] = {sa.x,sa.y,sa.z,sa.w,sb.x,sb.y,sb.z,sb.w};                   \
    float lv[8] = {la.x,la.y,la.z,la.w,lb.x,lb.y,lb.z,lb.w};                   \
    bf16x8 w;                                                                  \
    _Pragma("unroll")                                                          \
    for (int h = 0; h < 8; ++h) {                                              \
        float v = s1i + sv[h];                                                 \
        v = fmaxf(v, 0.01f * v);             /* leaky relu (scale-inv) */      \
        if (k0f + kc8 + h == ig) v = 0.f;    /* diag of e zeroed */            \
        w[h] = (short)f2bf(exp2_fast(v + lv[h]));                              \
    }                                                                          \
    *(bf16x8*)(LdsC + 98304 + (DN) * 8192 + bgoff) = w;                        \
}

#define COMPUTE(AB, BD) {                                                      \
    const char* La = LdsC + (AB) * 32768;                                      \
    const char* Lb = LdsC + 98304 + (BD) * 8192;                               \
    bf16x8 av[8], bv[4];                                                       \
    _Pragma("unroll")                                                          \
    for (int mi = 0; mi < 8; ++mi)                                             \
        av[mi] = *(const bf16x8*)(La + abase0 + mi * 1024);                    \
    _Pragma("unroll")                                                          \
    for (int ni = 0; ni < 4; ++ni)                                             \
        bv[ni] = *(const bf16x8*)(Lb + bbase0 + ni * 1024);                    \
    __builtin_amdgcn_s_setprio(1);                                             \
    _Pragma("unroll")                                                          \
    for (int ni = 0; ni < 4; ++ni)                                             \
        _Pragma("unroll")                                                      \
        for (int mi = 0; mi < 8; ++mi)                                         \
            acc[mi][ni] = __builtin_amdgcn_mfma_f32_16x16x32_bf16(             \
                av[mi], bv[ni], acc[mi][ni], 0, 0, 0);                         \
    __builtin_amdgcn_s_setprio(0);                                             \
}

__global__ __launch_bounds__(512, 2) void gemm_kernel(
    const unsigned short* __restrict__ Xb, const float* __restrict__ s1,
    const float* __restrict__ s2, const float* __restrict__ lrd,
    float* __restrict__ out)
{
    // A ring-3 96KB | B dbuf-2 16KB | s2s 4KB | lrds 4KB  = 120 KiB
    __shared__ __align__(16) char LdsC[122880];
    float* s2s  = (float*)(LdsC + 114688);
    float* lrds = (float*)(LdsC + 118784);

    const int tid = threadIdx.x, lane = tid & 63, wid = tid >> 6;
    const int wm = wid >> 1, wn = wid & 1;   // 4M x 2N waves, 128x64 each

    // 256 blocks: xcd = flat&7 (4 batches/XCD), nt = 8 N-tiles of 128.
    int flat  = blockIdx.x;
    int xcd   = flat & 7;
    int p     = flat >> 3;
    int b     = (p >> 3) * 8 + xcd;
    int nt    = p & 7;
    int n0    = nt * 128;

    const char* XgB = (const char*)(Xb + (size_t)b * LSEQ * NDIM);

    // A staging sources (pre-swizzled superrow involution, rule #21).
    // chunk c = tid + j*512 -> LDS byte c*16; superrow sr=c>>3, slot=c&7;
    // log_inner = (slot*16)^((sr&7)<<4); global row r = 2*sr + (li>=64).
    const char* srcp[4];
    #pragma unroll
    for (int j = 0; j < 4; ++j) {
        int c = tid + j * 512;
        int sr = c >> 3, slot = c & 7;
        int li = (slot * 16) ^ ((sr & 7) << 4);
        int r = sr * 2 + (li >> 6);
        srcp[j] = XgB + (size_t)r * 2048 + (li & 63);
    }

    // Fragment read bases (R6 scheme, measured 0 conflicts):
    // row r -> sr=r>>1, inner=((r&1)*64+kq*16)^((sr&7)<<4); sr&7 == (rsel>>1)&7.
    const int rsel = lane & 15, kq = lane >> 4;
    const int finner = (((rsel & 1) * 64) + kq * 16) ^ (((rsel >> 1) & 7) << 4);
    const int abase0 = (wm * 64 + (rsel >> 1)) * 128 + finner;   // A rows wm*128+mi*16+rsel
    const int bbase0 = (wn * 32 + (rsel >> 1)) * 128 + finner;   // B rows wn*64+ni*16+rsel

    // BGEN roles: row rr (one of 128), k-chunk kc8 (8 k's). 1 bf16x8/thread.
    const int rr   = wid * 16 + (lane & 15);
    const int kc8  = (lane >> 4) * 8;
    const int ig   = n0 + rr;
    const int bgoff = (rr >> 1) * 128 +
                      ((((rr & 1) * 64) + (lane >> 4) * 16) ^ (((rr >> 1) & 7) << 4));

    // panels: s2'/lrd' for batch b -> LDS (4KB each)
    {
        const float* s2g = s2 + (size_t)b * NDIM;
        const float* ldg = lrd + (size_t)b * NDIM;
        if (tid < 256) *(float4*)(s2s + tid * 4) = *(const float4*)(s2g + tid * 4);
        else *(float4*)(lrds + (tid - 256) * 4) = *(const float4*)(ldg + (tid - 256) * 4);
    }
    float s1i = s1[(size_t)b * NDIM + ig];

    STAGE(0); STAGE(1);       // A tiles 0,1 -> ring 0,1
    __syncthreads();          // panels + A0/A1 visible (prologue-only drain)

    f32x4 acc[8][4] = {};

    BGEN(0, 0);               // B tile 0
    LGKM0(); BARF();

    // main loop t=0..29: stage A(t+2), gen B(t+1), compute t.
    // End-of-iter WAITVM(4): drains A(t+1) (4 loads), leaves A(t+2) in
    // flight across the barrier — counted, never 0 (T4).
    // WAR: A ring buf (t+2)%3 == (t-1)%3 last read iter t-1 (closed by its
    // end barrier); B dbuf (t+1)&1 last read iter t-1 likewise.
    for (int t = 0; t < 30; ++t) {
        STAGE((t + 2) % 3);
        BGEN(t + 1, (t + 1) & 1);
        COMPUTE(t % 3, t & 1);
        WAITVM(4); LGKM0(); BARF();
    }
    // peeled t=30: no more stages
    BGEN(31, 1);
    COMPUTE(0, 0);            // tile 30: ring 30%3=0, dbuf 0
    WAITVM(0); LGKM0(); BARF();
    COMPUTE(1, 1);            // tile 31: ring 31%3=1, dbuf 1

    // epilogue: C/D layout col=lane&15, row=(lane>>4)*4+reg  [m89/m91 verified]
    float* outb = out + (size_t)b * LSEQ * NDIM + n0;
    const int rq = lane >> 4, cl = lane & 15;
    #pragma unroll
    for (int mi = 0; mi < 8; ++mi)
        #pragma unroll
        for (int ni = 0; ni < 4; ++ni) {
            int col = wn * 64 + ni * 16 + cl;
            #pragma unroll
            for (int r2 = 0; r2 < 4; ++r2) {
                int row = wm * 128 + mi * 16 + rq * 4 + r2;
                float v = acc[mi][ni][r2];
                outb[(size_t)row * NDIM + col] = 1.0f / (1.0f + __expf(-v));
            }
        }
}

#undef WAITVM
#undef LGKM0
#undef BARF
#undef STAGE
#undef BGEN
#undef COMPUTE

// ---------------------------------------------------------------------------
extern "C" void kernel_launch(void* const* d_in, const int* in_sizes, int n_in,
                              void* d_out, int out_size, void* d_ws, size_t ws_size,
                              hipStream_t stream) {
    (void)in_sizes; (void)n_in; (void)out_size; (void)ws_size;
    const float* X = (const float*)d_in[0];
    const float* W = (const float*)d_in[1];
    float* out = (float*)d_out;

    // workspace: s1|s2|lrd (32K floats) | P1|P2 (512K floats) | Xb bf16 32MB
    float* s1 = (float*)d_ws;
    float* s2 = s1 + BATCH * NDIM;
    float* lrd = s2 + BATCH * NDIM;
    float* P1 = lrd + BATCH * NDIM;
    float* P2 = P1 + (size_t)NSPLIT * BATCH * NDIM;
    unsigned short* Xb = (unsigned short*)(P2 + (size_t)NSPLIT * BATCH * NDIM);

    prep_kernel<<<dim3(NSPLIT, BATCH), 256, 0, stream>>>(X, W, Xb, P1, P2);
    stats_kernel<<<256, 256, 0, stream>>>(P1, P2, s1, s2, lrd);
    gemm_kernel<<<256, 512, 0, stream>>>(Xb, s1, s2, lrd, out);
}